// Round 1
// baseline (107.250 us; speedup 1.0000x reference)
//
#include <hip/hip_runtime.h>
#include <hip/hip_bf16.h>

// out[n,h] = x[n,h] * weight[h] + bias[h]
// N=16384, H=4096, fp32 in/out. Pure streaming: float4 loads/stores,
// grid-stride, weight/bias stay L2-resident (16 KiB each).

__global__ __launch_bounds__(256) void scale_shift_f32(
    const float4* __restrict__ x,
    const float4* __restrict__ w,
    const float4* __restrict__ b,
    float4* __restrict__ out,
    int total4, int h4mask) {
    int stride = gridDim.x * blockDim.x;
    for (int i = blockIdx.x * blockDim.x + threadIdx.x; i < total4; i += stride) {
        int h4 = i & h4mask;               // H/4 is a power of two (1024)
        float4 xv = x[i];
        float4 wv = w[h4];
        float4 bv = b[h4];
        float4 o;
        o.x = fmaf(xv.x, wv.x, bv.x);
        o.y = fmaf(xv.y, wv.y, bv.y);
        o.z = fmaf(xv.z, wv.z, bv.z);
        o.w = fmaf(xv.w, wv.w, bv.w);
        out[i] = o;
    }
}

extern "C" void kernel_launch(void* const* d_in, const int* in_sizes, int n_in,
                              void* d_out, int out_size, void* d_ws, size_t ws_size,
                              hipStream_t stream) {
    const float* x = (const float*)d_in[0];
    const float* w = (const float*)d_in[1];
    const float* b = (const float*)d_in[2];
    float* out = (float*)d_out;

    const int H = in_sizes[1];           // 4096
    const int total = out_size;          // N*H = 67,108,864
    const int total4 = total / 4;
    const int h4mask = H / 4 - 1;

    const int block = 256;
    int grid = (total4 + block - 1) / block;
    if (grid > 2048) grid = 2048;        // grid-stride the rest (256 CU × 8)

    scale_shift_f32<<<grid, block, 0, stream>>>(
        (const float4*)x, (const float4*)w, (const float4*)b,
        (float4*)out, total4, h4mask);
}